// Round 1
// baseline (560.255 us; speedup 1.0000x reference)
//
#include <hip/hip_runtime.h>
#include <hip/hip_bf16.h>

#define B_ 256
#define N_ 128
#define D_ 64

typedef short bf16x8 __attribute__((ext_vector_type(8)));
typedef short bf16x4 __attribute__((ext_vector_type(4)));
typedef float f32x4 __attribute__((ext_vector_type(4)));

// RNE float->bf16 bits (NaN irrelevant for this data)
static __device__ __forceinline__ short f2bf(float f) {
  unsigned u = __builtin_bit_cast(unsigned, f);
  u += 0x7FFFu + ((u >> 16) & 1u);
  return (short)(u >> 16);
}

static __device__ __forceinline__ float sigmoidf_fast(float x) {
  return __builtin_amdgcn_rcpf(1.0f + __expf(-x));
}

// Kernel 1: score[b,i,j] = 0.125 * sum_{d,e} q[b,i,d] * z[i,j,d,e] * k[b,j,e]
// z = clip(1.2*sigmoid(M)-0.1, 0, 1);  also accumulates l0 = sum sigmoid(M + (2/3)ln11)
// grid: (16 j-tiles, 128 i), block 256 = 4 waves.
// Per (i,j): MFMA computes C^T[e][b] = sum_d z[d][e] * q[b][d]  (M=e=64, N=b=256, K=d=64)
__global__ __launch_bounds__(256)
void score_k(const float* __restrict__ qg, const float* __restrict__ kg,
             const float* __restrict__ mat, float* __restrict__ score,
             float* __restrict__ l0g) {
  __shared__ short qs[B_ * 72];   // q_i bf16, [b][d], row stride 72 (16B-aligned rows)
  __shared__ short zs[D_ * 72];   // z bf16 TRANSPOSED: [e][d], row stride 72

  const int i    = blockIdx.y;
  const int j0   = blockIdx.x * 8;
  const int tid  = threadIdx.x;
  const int w    = tid >> 6;
  const int lane = tid & 63;
  const int quad = lane >> 4;
  const int c    = lane & 15;

  // ---- stage q_i (all 256 b) as bf16 ----
  {
    const int d4 = (tid & 15) * 4;
    const int bb = tid >> 4;
    for (int r = 0; r < 16; ++r) {
      const int b = r * 16 + bb;
      const float4 v = *(const float4*)(qg + ((size_t)b * (N_ * D_) + (size_t)i * D_ + d4));
      bf16x4 p;
      p[0] = f2bf(v.x); p[1] = f2bf(v.y); p[2] = f2bf(v.z); p[3] = f2bf(v.w);
      *(bf16x4*)(&qs[b * 72 + d4]) = p;
    }
  }

  float l0p = 0.0f;

  for (int jj = 0; jj < 8; ++jj) {
    const int j = j0 + jj;
    __syncthreads();  // previous iteration's readers done (also covers q staging on jj==0)

    // ---- stage z[i,j] : read 16 consecutive floats (fixed d, e0..e0+15), fuse gate, write transposed ----
    {
      const int d  = tid >> 2;         // 0..63
      const int e0 = (tid & 3) << 4;   // 0,16,32,48
      const float4* src = (const float4*)(mat + (((size_t)(i * N_ + j)) << 12) + ((size_t)tid << 4));
      float4 f[4];
      f[0] = src[0]; f[1] = src[1]; f[2] = src[2]; f[3] = src[3];
      const float* fe = (const float*)f;
      #pragma unroll
      for (int u = 0; u < 16; ++u) {
        const float x  = fe[u];
        const float sg = sigmoidf_fast(x);
        const float z  = fminf(fmaxf(sg * 1.2f - 0.1f, 0.0f), 1.0f);
        l0p += sigmoidf_fast(x + 1.5985969f);   // x - BETA*log(-GAMMA/ZETA) = x + (2/3)*ln(11)
        zs[(e0 + u) * 72 + d] = f2bf(z);
      }
    }
    __syncthreads();

    // ---- MFMA: C[e][b], wave w owns b in [64w, 64w+64) ----
    f32x4 acc[4][4];  // [et][btl]
    #pragma unroll
    for (int et = 0; et < 4; ++et)
      #pragma unroll
      for (int bt = 0; bt < 4; ++bt) acc[et][bt] = (f32x4){0.f, 0.f, 0.f, 0.f};

    #pragma unroll
    for (int ks = 0; ks < 2; ++ks) {
      const int db = ks * 32 + quad * 8;
      bf16x8 af[4];
      #pragma unroll
      for (int et = 0; et < 4; ++et)
        af[et] = *(const bf16x8*)(&zs[(et * 16 + c) * 72 + db]);   // A[m=e=lane&15][k=d]
      #pragma unroll
      for (int bt = 0; bt < 4; ++bt) {
        const bf16x8 bfr = *(const bf16x8*)(&qs[(w * 64 + bt * 16 + c) * 72 + db]); // B[k=d][n=b=lane&15]
        #pragma unroll
        for (int et = 0; et < 4; ++et)
          acc[et][bt] = __builtin_amdgcn_mfma_f32_16x16x32_bf16(af[et], bfr, acc[et][bt], 0, 0, 0);
      }
    }

    // ---- epilogue: score[b,i,j] = 0.125 * sum_e C[e][b] * k[b,j,e] ----
    // lane reg r of acc[et][bt] holds C[e = et*16 + quad*4 + r][b = 64w + bt*16 + c]
    #pragma unroll
    for (int bt = 0; bt < 4; ++bt) {
      const int b = w * 64 + bt * 16 + c;
      const float* kp = kg + ((size_t)b * (N_ * D_) + (size_t)j * D_);
      float s = 0.0f;
      #pragma unroll
      for (int et = 0; et < 4; ++et) {
        const float4 kv = *(const float4*)(kp + et * 16 + quad * 4);
        s += acc[et][bt][0] * kv.x + acc[et][bt][1] * kv.y +
             acc[et][bt][2] * kv.z + acc[et][bt][3] * kv.w;
      }
      s += __shfl_xor(s, 16, 64);  // reduce across quads (e-groups)
      s += __shfl_xor(s, 32, 64);
      if (quad == 0)
        score[(size_t)b * (N_ * N_) + (size_t)i * N_ + j] = s * 0.125f;
    }
  }

  // ---- l0 wave reduction + device atomic ----
  #pragma unroll
  for (int off = 32; off >= 1; off >>= 1) l0p += __shfl_xor(l0p, off, 64);
  if (lane == 0) atomicAdd(l0g, l0p);
}

// Kernel 2: softmax over j + out = attn @ v via MFMA (M=16 i, N=64 d, K=128 j per wave)
// grid: (2 halves, 256 b), block 256 = 4 waves; wave handles 16 i-rows.
__global__ __launch_bounds__(256)
void attn_k(const float* __restrict__ score, const float* __restrict__ vg,
            const float* __restrict__ l0g, float* __restrict__ out) {
  __shared__ short ps[4][16 * 136];  // per-wave p (softmax probs, /l folded in), [i][j], stride 136

  const int b    = blockIdx.y;
  const int half = blockIdx.x;
  const int tid  = threadIdx.x;
  const int w    = tid >> 6;
  const int lane = tid & 63;
  const int quad = lane >> 4;
  const int c    = lane & 15;
  const int i0   = half * 64 + w * 16;

  // ---- softmax for this wave's 16 rows ----
  for (int t = 0; t < 16; ++t) {
    const int i = i0 + t;
    const float* sp = score + (size_t)b * (N_ * N_) + (size_t)i * N_;
    const float s0 = sp[lane], s1 = sp[lane + 64];
    float m = fmaxf(s0, s1);
    #pragma unroll
    for (int off = 32; off >= 1; off >>= 1) m = fmaxf(m, __shfl_xor(m, off, 64));
    const float e0 = __expf(s0 - m), e1 = __expf(s1 - m);
    float l = e0 + e1;
    #pragma unroll
    for (int off = 32; off >= 1; off >>= 1) l += __shfl_xor(l, off, 64);
    const float rl = __builtin_amdgcn_rcpf(l);
    ps[w][t * 136 + lane]      = f2bf(e0 * rl);
    ps[w][t * 136 + lane + 64] = f2bf(e1 * rl);
  }
  __syncthreads();  // cheap safety: LDS writes visible before fragment reads

  f32x4 oacc[4];
  #pragma unroll
  for (int dt = 0; dt < 4; ++dt) oacc[dt] = (f32x4){0.f, 0.f, 0.f, 0.f};

  #pragma unroll
  for (int kt = 0; kt < 4; ++kt) {
    const bf16x8 af = *(const bf16x8*)(&ps[w][c * 136 + kt * 32 + quad * 8]); // A[m=i=lane&15][k=j]
    const int jb = kt * 32 + quad * 8;
    #pragma unroll
    for (int dt = 0; dt < 4; ++dt) {
      const float* vp = vg + (size_t)b * (N_ * D_) + (size_t)jb * D_ + dt * 16 + c;
      bf16x8 bfr;                                   // B[k=j][n=d=lane&15]
      #pragma unroll
      for (int u = 0; u < 8; ++u) bfr[u] = f2bf(vp[u * D_]);
      oacc[dt] = __builtin_amdgcn_mfma_f32_16x16x32_bf16(af, bfr, oacc[dt], 0, 0, 0);
    }
  }

  // C[i][d]: row i_local = quad*4 + r, col d = dt*16 + c
  #pragma unroll
  for (int dt = 0; dt < 4; ++dt)
    #pragma unroll
    for (int r = 0; r < 4; ++r) {
      const int i = i0 + quad * 4 + r;
      out[(size_t)b * (N_ * D_) + (size_t)i * D_ + dt * 16 + c] = oacc[dt][r];
    }

  if (b == 0 && half == 0 && tid == 0)
    out[(size_t)B_ * N_ * D_] = l0g[0];
}

extern "C" void kernel_launch(void* const* d_in, const int* in_sizes, int n_in,
                              void* d_out, int out_size, void* d_ws, size_t ws_size,
                              hipStream_t stream) {
  const float* q   = (const float*)d_in[0];
  const float* k   = (const float*)d_in[1];
  const float* v   = (const float*)d_in[2];
  const float* mat = (const float*)d_in[3];
  float* out   = (float*)d_out;
  float* score = (float*)d_ws;                              // 256*128*128 floats = 16.78 MB
  float* l0g   = score + (size_t)B_ * N_ * N_;

  hipMemsetAsync(l0g, 0, sizeof(float), stream);
  score_k<<<dim3(16, 128), 256, 0, stream>>>(q, k, mat, score, l0g);
  attn_k<<<dim3(2, 256), 256, 0, stream>>>(score, v, l0g, out);
}

// Round 2
// 529.914 us; speedup vs baseline: 1.0573x; 1.0573x over previous
//
#include <hip/hip_runtime.h>
#include <hip/hip_bf16.h>

#define B_ 256
#define N_ 128
#define D_ 64
#define JT 16   // j-tile per score_k block

typedef short bf16x8 __attribute__((ext_vector_type(8)));
typedef short bf16x4 __attribute__((ext_vector_type(4)));
typedef float f32x4 __attribute__((ext_vector_type(4)));

// RNE float->bf16 bits
static __device__ __forceinline__ short f2bf(float f) {
  unsigned u = __builtin_bit_cast(unsigned, f);
  u += 0x7FFFu + ((u >> 16) & 1u);
  return (short)(u >> 16);
}

// LDS-only barrier: wait ds ops, do NOT drain vmcnt (keeps global prefetch in flight).
// __syncthreads() would emit s_waitcnt vmcnt(0) and kill the pipeline.
static __device__ __forceinline__ void barrier_lds() {
  asm volatile("s_waitcnt lgkmcnt(0)\n\ts_barrier" ::: "memory");
}

// Kernel 1: score[b,i,j] = 0.125 * sum_{d,e} q[b,i,d] * z[i,j,d,e] * k[b,j,e]
// grid (8 j-tiles, 128 i), block 256 = 4 waves. Matrix streamed with 1-deep
// register prefetch; MFMA computes C[e][b] = Z^T q^T per (i,j); epilogue dots C
// against k[b,j,:] and accumulates 4 j per lane -> 16B coalesced score stores.
__global__ __launch_bounds__(256)
void score_k(const float* __restrict__ qg, const float* __restrict__ kg,
             const float* __restrict__ mat, float* __restrict__ score,
             float* __restrict__ l0g) {
  __shared__ short qs[B_ * 72];   // q_i bf16 [b][d], stride 72 (16B-aligned rows)
  __shared__ short zs[D_ * 72];   // z bf16 transposed [e][d], stride 72

  const int i    = blockIdx.y;
  const int j0   = blockIdx.x * JT;
  const int tid  = threadIdx.x;
  const int w    = tid >> 6;
  const int lane = tid & 63;
  const int quad = lane >> 4;
  const int c    = lane & 15;

  // ---- stage q_i (all 256 b) as bf16 ----
  {
    const int d4 = (tid & 15) * 4;
    const int bb = tid >> 4;
    #pragma unroll
    for (int r = 0; r < 16; ++r) {
      const int b = r * 16 + bb;
      const float4 v = *(const float4*)(qg + ((size_t)b * (N_ * D_) + (size_t)i * D_ + d4));
      bf16x4 p;
      p[0] = f2bf(v.x); p[1] = f2bf(v.y); p[2] = f2bf(v.z); p[3] = f2bf(v.w);
      *(bf16x4*)(&qs[b * 72 + d4]) = p;
    }
  }

  const int d0 = (tid >> 4) * 4;   // 0..60 : this thread's 4 d-rows
  const int e0 = (tid & 15) * 4;   // 0..60 : this thread's 4 e-cols

  // ---- prefetch tile jj=0 into registers ----
  float4 F[4];
  {
    const float* src = mat + (((size_t)(i * N_ + j0)) << 12);
    #pragma unroll
    for (int r = 0; r < 4; ++r)
      F[r] = *(const float4*)(src + (d0 + r) * 64 + e0);
  }

  float l0p = 0.0f;

  for (int jo = 0; jo < 4; ++jo) {
    float sacc[4];
    #pragma unroll
    for (int ji = 0; ji < 4; ++ji) {
      const int jj = jo * 4 + ji;

      // ---- gate F -> zb (1 exp + 2 rcp per element; shares e^-x between sigmoids) ----
      short zb[4][4];   // [d-row r][e-col u]
      #pragma unroll
      for (int r = 0; r < 4; ++r) {
        #pragma unroll
        for (int u = 0; u < 4; ++u) {
          const float x  = ((const float*)&F[r])[u];
          const float t  = __expf(-x);
          const float sg = __builtin_amdgcn_rcpf(1.0f + t);
          const float z  = fminf(fmaxf(fmaf(sg, 1.2f, -0.1f), 0.0f), 1.0f);
          l0p += __builtin_amdgcn_rcpf(fmaf(t, 0.2021805f, 1.0f)); // sigmoid(x+(2/3)ln11)
          zb[r][u] = f2bf(z);
        }
      }

      // ---- issue next tile load (stays in flight across LDS barriers + MFMA) ----
      if (jj < JT - 1) {
        const float* src = mat + (((size_t)(i * N_ + j0 + jj + 1)) << 12);
        #pragma unroll
        for (int r = 0; r < 4; ++r)
          F[r] = *(const float4*)(src + (d0 + r) * 64 + e0);
      }

      // ---- write z^T to LDS: 4x ds_write_b64 ----
      #pragma unroll
      for (int u = 0; u < 4; ++u) {
        bf16x4 p;
        p[0] = zb[0][u]; p[1] = zb[1][u]; p[2] = zb[2][u]; p[3] = zb[3][u];
        *(bf16x4*)(&zs[(e0 + u) * 72 + d0]) = p;
      }
      barrier_lds();

      // ---- MFMA: C[e][b], wave w owns b in [64w, 64w+64) ----
      f32x4 acc[4][4];
      #pragma unroll
      for (int et = 0; et < 4; ++et)
        #pragma unroll
        for (int bt = 0; bt < 4; ++bt) acc[et][bt] = (f32x4){0.f, 0.f, 0.f, 0.f};

      #pragma unroll
      for (int ks = 0; ks < 2; ++ks) {
        const int db = ks * 32 + quad * 8;
        bf16x8 af[4];
        #pragma unroll
        for (int et = 0; et < 4; ++et)
          af[et] = *(const bf16x8*)(&zs[(et * 16 + c) * 72 + db]);  // A[m=e][k=d]
        #pragma unroll
        for (int bt = 0; bt < 4; ++bt) {
          const bf16x8 bfr = *(const bf16x8*)(&qs[(w * 64 + bt * 16 + c) * 72 + db]); // B[k=d][n=b]
          #pragma unroll
          for (int et = 0; et < 4; ++et)
            acc[et][bt] = __builtin_amdgcn_mfma_f32_16x16x32_bf16(af[et], bfr, acc[et][bt], 0, 0, 0);
        }
      }

      // ---- epilogue: s(b) = sum_e C[e][b] * k[b,j,e]  (k L2-resident per XCD) ----
      const int j = j0 + jj;
      float s[4];
      #pragma unroll
      for (int bt = 0; bt < 4; ++bt) {
        const int b = w * 64 + bt * 16 + c;
        const float* kp = kg + ((size_t)b * (N_ * D_) + (size_t)j * D_);
        float sv = 0.0f;
        #pragma unroll
        for (int et = 0; et < 4; ++et) {
          const float4 kv = *(const float4*)(kp + et * 16 + quad * 4);
          sv += acc[et][bt][0] * kv.x + acc[et][bt][1] * kv.y +
                acc[et][bt][2] * kv.z + acc[et][bt][3] * kv.w;
        }
        s[bt] = sv;
      }
      barrier_lds();  // zs reads done before next iteration's writes

      // butterfly over quads -> every lane holds full sums for all 4 bt
      #pragma unroll
      for (int bt = 0; bt < 4; ++bt) {
        s[bt] += __shfl_xor(s[bt], 16, 64);
        s[bt] += __shfl_xor(s[bt], 32, 64);
      }
      // lane owns b = w*64 + lane  ->  bt = quad
      const float sel = quad == 0 ? s[0] : quad == 1 ? s[1] : quad == 2 ? s[2] : s[3];
      sacc[ji] = sel * 0.125f;
    }

    // ---- coalesced 16B store: lane owns row b_own, 4 consecutive j ----
    {
      const int b_own = w * 64 + lane;
      f32x4 o;
      o[0] = sacc[0]; o[1] = sacc[1]; o[2] = sacc[2]; o[3] = sacc[3];
      *(f32x4*)(score + (size_t)b_own * (N_ * N_) + (size_t)i * N_ + (j0 + jo * 4)) = o;
    }
  }

  // ---- l0 reduction ----
  #pragma unroll
  for (int off = 32; off >= 1; off >>= 1) l0p += __shfl_xor(l0p, off, 64);
  if (lane == 0) atomicAdd(l0g, l0p);
}

// Kernel 2: softmax over j + out = attn @ v via MFMA.
// grid (2 halves, 256 b), block 256 = 4 waves; wave handles 16 i-rows.
// v staged once per block as bf16 v^T in LDS -> b128 fragment reads.
__global__ __launch_bounds__(256)
void attn_k(const float* __restrict__ score, const float* __restrict__ vg,
            const float* __restrict__ l0g, float* __restrict__ out) {
  __shared__ short vt[D_ * 136];     // v^T [d][j], stride 136 (16B-aligned rows)
  __shared__ short ps[4][16 * 136];  // per-wave probs [i][j]

  const int b    = blockIdx.y;
  const int half = blockIdx.x;
  const int tid  = threadIdx.x;
  const int w    = tid >> 6;
  const int lane = tid & 63;
  const int quad = lane >> 4;
  const int c    = lane & 15;
  const int i0   = half * 64 + w * 16;

  // ---- stage v^T (8 coalesced float4 per thread, transpose into LDS) ----
  {
    const float* vb = vg + (size_t)b * (N_ * D_);
    #pragma unroll
    for (int r = 0; r < 8; ++r) {
      const int f  = r * 256 + tid;    // float4 index 0..2047
      const int j  = f >> 4;
      const int dd = (f & 15) * 4;
      const float4 vv = *(const float4*)(vb + j * D_ + dd);
      vt[(dd + 0) * 136 + j] = f2bf(vv.x);
      vt[(dd + 1) * 136 + j] = f2bf(vv.y);
      vt[(dd + 2) * 136 + j] = f2bf(vv.z);
      vt[(dd + 3) * 136 + j] = f2bf(vv.w);
    }
  }

  // ---- softmax: batch all row loads first, then 16 independent reductions ----
  float s0[16], s1[16];
  const float* sp0 = score + (size_t)b * (N_ * N_) + (size_t)i0 * N_;
  #pragma unroll
  for (int t = 0; t < 16; ++t) {
    s0[t] = sp0[t * N_ + lane];
    s1[t] = sp0[t * N_ + lane + 64];
  }
  #pragma unroll
  for (int t = 0; t < 16; ++t) {
    float m = fmaxf(s0[t], s1[t]);
    #pragma unroll
    for (int off = 32; off >= 1; off >>= 1) m = fmaxf(m, __shfl_xor(m, off, 64));
    const float e0 = __expf(s0[t] - m), e1 = __expf(s1[t] - m);
    float l = e0 + e1;
    #pragma unroll
    for (int off = 32; off >= 1; off >>= 1) l += __shfl_xor(l, off, 64);
    const float rl = __builtin_amdgcn_rcpf(l);
    ps[w][t * 136 + lane]      = f2bf(e0 * rl);
    ps[w][t * 136 + lane + 64] = f2bf(e1 * rl);
  }
  barrier_lds();  // vt visible to all waves (ps is same-wave -> lgkmcnt covers it)

  // ---- PV: M=16 i, N=64 d, K=128 j ----
  f32x4 oacc[4];
  #pragma unroll
  for (int dt = 0; dt < 4; ++dt) oacc[dt] = (f32x4){0.f, 0.f, 0.f, 0.f};

  #pragma unroll
  for (int kt = 0; kt < 4; ++kt) {
    const int jb = kt * 32 + quad * 8;
    const bf16x8 af = *(const bf16x8*)(&ps[w][c * 136 + jb]);       // A[m=i][k=j]
    #pragma unroll
    for (int dt = 0; dt < 4; ++dt) {
      const bf16x8 bfr = *(const bf16x8*)(&vt[(dt * 16 + c) * 136 + jb]); // B[k=j][n=d]
      oacc[dt] = __builtin_amdgcn_mfma_f32_16x16x32_bf16(af, bfr, oacc[dt], 0, 0, 0);
    }
  }

  // C[i][d]: row = quad*4 + r, col = dt*16 + c
  #pragma unroll
  for (int dt = 0; dt < 4; ++dt)
    #pragma unroll
    for (int r = 0; r < 4; ++r) {
      const int i = i0 + quad * 4 + r;
      out[(size_t)b * (N_ * D_) + (size_t)i * D_ + dt * 16 + c] = oacc[dt][r];
    }

  if (b == 0 && half == 0 && tid == 0)
    out[(size_t)B_ * N_ * D_] = l0g[0];
}

extern "C" void kernel_launch(void* const* d_in, const int* in_sizes, int n_in,
                              void* d_out, int out_size, void* d_ws, size_t ws_size,
                              hipStream_t stream) {
  const float* q   = (const float*)d_in[0];
  const float* k   = (const float*)d_in[1];
  const float* v   = (const float*)d_in[2];
  const float* mat = (const float*)d_in[3];
  float* out   = (float*)d_out;
  float* score = (float*)d_ws;                 // 256*128*128 floats = 16.78 MB
  float* l0g   = score + (size_t)B_ * N_ * N_;

  hipMemsetAsync(l0g, 0, sizeof(float), stream);
  score_k<<<dim3(N_ / JT, N_), 256, 0, stream>>>(q, k, mat, score, l0g);
  attn_k<<<dim3(2, B_), 256, 0, stream>>>(score, v, l0g, out);
}